// Round 4
// baseline (481.926 us; speedup 1.0000x reference)
//
#include <hip/hip_runtime.h>
#include <cstdint>

#define DEV __device__ __forceinline__

using short8 = __attribute__((ext_vector_type(8))) short;
using f32x4  = __attribute__((ext_vector_type(4))) float;

#define MFMA __builtin_amdgcn_mfma_f32_16x16x32_bf16

DEV float bf2f(unsigned short u){
  union { unsigned int i; float f; } v; v.i = ((unsigned int)u) << 16; return v.f;
}
DEV unsigned short f2bf(float f){
  union { float f; unsigned int i; } v; v.f = f;
  unsigned int x = v.i;
  return (unsigned short)((x + 0x7fffu + ((x >> 16) & 1u)) >> 16);
}

// p (0..3135) -> region (0..48), token (0..63)
DEV void p2rt(int p, int& reg, int& tok){
  int y = p / 56, x = p - y*56;
  reg = (y>>3)*7 + (x>>3);
  tok = ((y&7)<<3) + (x&7);
}

// ---------------- prep: bf16 (hi/lo) splits of weights ----------------
__global__ __launch_bounds__(256) void k_prep(const float* __restrict__ w_qkv,
                                              const float* __restrict__ w_out,
                                              unsigned short* __restrict__ wqh,
                                              unsigned short* __restrict__ woh,
                                              unsigned short* __restrict__ wol){
  int i = blockIdx.x*256 + threadIdx.x;
  if (i < 196608){
    wqh[i] = f2bf(w_qkv[i]);
  } else {
    int j = i - 196608;
    if (j < 65536){
      float v = w_out[j];
      unsigned short h = f2bf(v);
      woh[j] = h;
      wol[j] = f2bf(v - bf2f(h));
    }
  }
}

// ---------------- region means of x (fp32 exact, coalesced rows) ----------------
__global__ __launch_bounds__(256) void k_xbar(const float* __restrict__ x,
                                              float* __restrict__ xbar){
  // grid (7 ry, 16 n); 256 thr = 4 c-groups x 64 lanes
  const int ry = blockIdx.x, n = blockIdx.y;
  const int t = threadIdx.x, cg = t>>6, lane = t&63;
  for (int ci = 0; ci < 64; ++ci){
    int c = ci*4 + cg;
    const float* base = x + ((size_t)n*256 + c)*3136 + ry*8*56;
    float acc = 0.f;
    if (lane < 56){
      #pragma unroll
      for (int yy = 0; yy < 8; ++yy) acc += base[yy*56 + lane];
    }
    acc += __shfl_xor(acc, 1, 64);
    acc += __shfl_xor(acc, 2, 64);
    acc += __shfl_xor(acc, 4, 64);
    if ((lane&7) == 0 && lane < 56)
      xbar[((size_t)n*49 + ry*7 + (lane>>3))*256 + c] = acc * (1.0f/64.0f);
  }
}

// ---------------- q_r / k_r = W_{q,k} * xbar + b (fp32; W read once) ----------------
__global__ __launch_bounds__(256) void k_qrkr(const float* __restrict__ xbar,
                                              const float* __restrict__ w_qkv,
                                              const float* __restrict__ b_qkv,
                                              float* __restrict__ q_r,
                                              float* __restrict__ k_r){
  // grid (8 wchunks, 16 n); 256 thr = 64 rows x 4 k-lanes
  __shared__ float4 xb4[3136]; // 49 regions x 64 float4
  const int wb = blockIdx.x, n = blockIdx.y, t = threadIdx.x;
  {
    const float4* src = (const float4*)(xbar + (size_t)n*12544);
    for (int i = t; i < 3136; i += 256) xb4[i] = src[i];
  }
  const int wrow = wb*64 + (t>>2), kl = t&3;
  float4 wreg[16];
  {
    const float4* wsrc = (const float4*)(w_qkv + (size_t)wrow*256) + kl*16;
    #pragma unroll
    for (int i = 0; i < 16; ++i) wreg[i] = wsrc[i];
  }
  __syncthreads();
  const float bias = b_qkv[wrow];
  for (int reg = 0; reg < 49; ++reg){
    float s = 0.f;
    #pragma unroll
    for (int i = 0; i < 16; ++i){
      float4 a = wreg[i], b = xb4[reg*64 + kl*16 + i];
      s += a.x*b.x + a.y*b.y + a.z*b.z + a.w*b.w;
    }
    s += __shfl_xor(s, 1, 64);
    s += __shfl_xor(s, 2, 64);
    if (kl == 0){
      if (wrow < 256) q_r[((size_t)n*49 + reg)*256 + wrow] = s + bias;
      else            k_r[((size_t)n*49 + reg)*256 + wrow - 256] = s + bias;
    }
  }
}

// ---------------- routing scores + top-4 (ties: lowest index first) ----------------
__global__ __launch_bounds__(64) void k_topk(const float* __restrict__ q_r,
                                             const float* __restrict__ k_r,
                                             int* __restrict__ idx){
  __shared__ float sc[49];
  const int qreg = blockIdx.x, n = blockIdx.y, l = threadIdx.x;
  const float* qrow = q_r + ((size_t)n*49 + qreg)*256;
  const float q0 = qrow[l], q1 = qrow[l+64], q2 = qrow[l+128], q3 = qrow[l+192];
  for (int kr = 0; kr < 49; ++kr){
    const float* krow = k_r + ((size_t)n*49 + kr)*256;
    float s = q0*krow[l] + q1*krow[l+64] + q2*krow[l+128] + q3*krow[l+192];
    #pragma unroll
    for (int m = 1; m < 64; m <<= 1) s += __shfl_xor(s, m, 64);
    if (l == 0) sc[kr] = s;
  }
  __syncthreads();
  if (l == 0){
    #pragma unroll
    for (int s = 0; s < 4; ++s){
      float best = -3.4e38f; int bi = 0;
      for (int kr = 0; kr < 49; ++kr) if (sc[kr] > best){ best = sc[kr]; bi = kr; }
      idx[((size_t)n*49 + qreg)*4 + s] = bi;
      sc[bi] = -3.4e38f;
    }
  }
}

// ---------------- qkv 1x1 conv GEMM -> region-major q/k/v ----------------
__global__ __launch_bounds__(256) void k_qkv(const float* __restrict__ x,
                                             const unsigned short* __restrict__ wqh,
                                             const float* __restrict__ b_qkv,
                                             unsigned short* __restrict__ q_rm,
                                             unsigned short* __restrict__ k_rm,
                                             unsigned short* __restrict__ v_rm,
                                             unsigned short* __restrict__ v_cm){
  // grid (49 p-tiles, 16 n)
  __shared__ unsigned short xl[64*256]; // [p][c], idx ^= (p&15)<<3
  const int pb = blockIdx.x*64, n = blockIdx.y;
  const int t = threadIdx.x, w = t>>6, g = (t>>4)&3, c16 = t&15;
  {
    const int pq = (t & 15)*4, cc = t >> 4;
    const size_t xb = ((size_t)n*256)*3136 + pb + pq;
    for (int ci = 0; ci < 16; ++ci){
      int c = ci*16 + cc;
      float4 v4 = *reinterpret_cast<const float4*>(x + xb + (size_t)c*3136);
      xl[((pq+0)*256 + c) ^ (((pq+0)&15)<<3)] = f2bf(v4.x);
      xl[((pq+1)*256 + c) ^ (((pq+1)&15)<<3)] = f2bf(v4.y);
      xl[((pq+2)*256 + c) ^ (((pq+2)&15)<<3)] = f2bf(v4.z);
      xl[((pq+3)*256 + c) ^ (((pq+3)&15)<<3)] = f2bf(v4.w);
    }
  }
  __syncthreads();

  for (int ot = 0; ot < 12; ++ot){
    const int os = ot*64 + w*16;
    f32x4 acc[4] = {};
    const unsigned short* wbase = wqh + (size_t)(os + c16)*256;
    #pragma unroll
    for (int kc = 0; kc < 8; ++kc){
      short8 wf = *reinterpret_cast<const short8*>(wbase + kc*32 + 8*g);
      #pragma unroll
      for (int pt = 0; pt < 4; ++pt){
        int p = pt*16 + c16;
        short8 xf = *reinterpret_cast<const short8*>(&xl[(p*256 + kc*32 + 8*g) ^ ((p&15)<<3)]);
        if (ot >= 8) acc[pt] = MFMA(wf, xf, acc[pt], 0, 0, 0);
        else         acc[pt] = MFMA(xf, wf, acc[pt], 0, 0, 0);
      }
    }
    if (ot < 8){
      // D rows = p-local (4g+r), cols = o-local (c16)
      const int o = os + c16;
      const float bias = b_qkv[o];
      unsigned short* dst = (o < 256) ? q_rm : k_rm;
      const int oc = o & 255;
      const int hh = oc >> 5, dd = oc & 31;
      const size_t hbase = ((size_t)(n*8 + hh))*49;
      #pragma unroll
      for (int pt = 0; pt < 4; ++pt)
        #pragma unroll
        for (int r = 0; r < 4; ++r){
          int p = pb + pt*16 + 4*g + r;
          int reg, tok; p2rt(p, reg, tok);
          dst[(hbase + reg)*2048 + tok*32 + dd] = f2bf(acc[pt][r] + bias);
        }
    } else {
      // D rows = o-local (4g+r), cols = p-local (c16)
      #pragma unroll
      for (int pt = 0; pt < 4; ++pt){
        int p = pb + pt*16 + c16;
        int reg, tok; p2rt(p, reg, tok);
        #pragma unroll
        for (int r = 0; r < 4; ++r){
          int o = os + 4*g + r;
          int c = o - 512;
          int hh = c >> 5, ch = c & 31;
          unsigned short bv = f2bf(acc[pt][r] + b_qkv[o]);
          v_cm[((size_t)n*256 + c)*3136 + p] = bv;
          v_rm[(((size_t)(n*8 + hh))*49 + reg)*2048 + ch*64 + tok] = bv;
        }
      }
    }
  }
}

// ---------------- attention + fused LEPE per (n, head, region) ----------------
// K/V staged in LDS (coalesced region-major loads); one barrier total.
__global__ __launch_bounds__(256) void k_attn(const unsigned short* __restrict__ q_rm,
                                              const unsigned short* __restrict__ k_rm,
                                              const unsigned short* __restrict__ v_rm,
                                              const unsigned short* __restrict__ v_cm,
                                              const int* __restrict__ idx,
                                              const float* __restrict__ w_lepe,
                                              const float* __restrict__ b_lepe,
                                              unsigned short* __restrict__ att_hi,
                                              unsigned short* __restrict__ att_lo){
  __shared__ unsigned short Kl[256*40];   // [gathered tok][32d], 80B row stride
  __shared__ unsigned short Vl[32*264];   // [ch][gathered tok], 264 stride
  __shared__ unsigned short Pw[4*2048];   // per-wave [16 q][128 k], swizzled
  __shared__ unsigned short halo[4160];   // [32 c][10 y][13 x]
  __shared__ float wl_s[288];
  __shared__ float bl_s[32];

  // XCD-aware remap: all 49 qreg-blocks of one (h,n) on one XCD, consecutive.
  const int lin = blockIdx.x + 49*(blockIdx.y + 8*blockIdx.z);
  const int xcd = lin & 7, j = lin >> 3;
  const int jq = j / 49;
  const int qreg = j - jq*49;
  const int hn = jq*8 + xcd;
  const int h = hn & 7, n = hn >> 3;

  const int t = threadIdx.x, w = t>>6, g = (t>>4)&3, c16 = t&15;
  const int ry = qreg/7, rx = qreg%7;
  const int gy0 = ry*8, gx0 = rx*8;

  int regs[4];
  #pragma unroll
  for (int s = 0; s < 4; ++s) regs[s] = idx[((size_t)n*49 + qreg)*4 + s];

  const size_t hb = ((size_t)(n*8 + h))*49;

  // ---- stage K: 4 regions x 64 tok x 64B, coalesced ----
  {
    const int rr = t>>6, tloc = t&63;
    const unsigned short* src = k_rm + (hb + regs[rr])*2048 + tloc*32;
    unsigned short* dst = &Kl[(rr*64 + tloc)*40];
    #pragma unroll
    for (int jj = 0; jj < 4; ++jj)
      *reinterpret_cast<short8*>(dst + jj*8) = *reinterpret_cast<const short8*>(src + jj*8);
  }
  // ---- stage V: 4 regions x 32ch x 64tok, coalesced ----
  {
    const int ch = t>>3, tl8 = (t&7)*8;
    #pragma unroll
    for (int rr = 0; rr < 4; ++rr){
      const unsigned short* src = v_rm + (hb + regs[rr])*2048 + ch*64 + tl8;
      *reinterpret_cast<short8*>(&Vl[ch*264 + rr*64 + tl8]) =
          *reinterpret_cast<const short8*>(src);
    }
  }
  // ---- stage LEPE weights + v halo ----
  wl_s[t < 288 ? t : 0] = w_lepe[h*288 + (t < 288 ? t : 0)];
  if (t < 32){
    wl_s[256 + t] = w_lepe[h*288 + 256 + t];
    bl_s[t] = b_lepe[h*32 + t];
  }
  for (int seg = t; seg < 320; seg += 256){
    int c = seg/10, row = seg - (seg/10)*10;
    int yy = gy0 + row - 1;
    unsigned short* drow = &halo[c*130 + row*13];
    if (yy < 0 || yy > 55){
      #pragma unroll
      for (int jj = 0; jj < 10; ++jj) drow[jj] = 0;
    } else {
      const unsigned short* src = v_cm + ((size_t)n*256 + h*32 + c)*3136 + yy*56 + gx0 - 1;
      #pragma unroll
      for (int jj = 0; jj < 10; ++jj){
        int xx = gx0 - 1 + jj;
        drow[jj] = (xx >= 0 && xx < 56) ? src[jj] : 0;
      }
    }
  }
  __syncthreads();

  // ---- Q frag (contiguous region-major global read) ----
  const int qtok = w*16 + c16;
  short8 qf = *reinterpret_cast<const short8*>(q_rm + (hb + qreg)*2048 + qtok*32 + 8*g);

  // ---- QK^T from LDS ----
  f32x4 s_acc[16];
  #pragma unroll
  for (int f = 0; f < 16; ++f){
    short8 kf = *reinterpret_cast<const short8*>(&Kl[(f*16 + c16)*40 + 8*g]);
    f32x4 z = {0.f, 0.f, 0.f, 0.f};
    s_acc[f] = MFMA(qf, kf, z, 0, 0, 0);
  }
  const float scale = 0.1767766952966369f; // 32^-0.5
  #pragma unroll
  for (int f = 0; f < 16; ++f) s_acc[f] = s_acc[f] * scale;

  // ---- softmax over 256 keys per row (row = w*16 + 4g + r) ----
  float inv[4];
  #pragma unroll
  for (int r = 0; r < 4; ++r){
    float m = -3.4e38f;
    #pragma unroll
    for (int f = 0; f < 16; ++f) m = fmaxf(m, s_acc[f][r]);
    #pragma unroll
    for (int d = 1; d < 16; d <<= 1) m = fmaxf(m, __shfl_xor(m, d, 64));
    float su = 0.f;
    #pragma unroll
    for (int f = 0; f < 16; ++f){ float e = __expf(s_acc[f][r] - m); s_acc[f][r] = e; su += e; }
    #pragma unroll
    for (int d = 1; d < 16; d <<= 1) su += __shfl_xor(su, d, 64);
    inv[r] = 1.0f / su;
  }

  // ---- PV in two k-halves: per-wave P staging (no block barrier) ----
  f32x4 oacc[2] = {};
  unsigned short* wb2 = &Pw[w*2048];
  #pragma unroll
  for (int h2 = 0; h2 < 2; ++h2){
    #pragma unroll
    for (int f2 = 0; f2 < 8; ++f2){
      int f = 8*h2 + f2;
      #pragma unroll
      for (int r = 0; r < 4; ++r){
        int q = 4*g + r;
        wb2[(q*128 + f2*16 + c16) ^ ((q&7)<<3)] = f2bf(s_acc[f][r] * inv[r]);
      }
    }
    asm volatile("s_waitcnt lgkmcnt(0)" ::: "memory");
    __builtin_amdgcn_sched_barrier(0);
    #pragma unroll
    for (int tcl = 0; tcl < 4; ++tcl){
      const int tc = 4*h2 + tcl;
      short8 pf = *reinterpret_cast<const short8*>(&wb2[(c16*128 + tcl*32 + 8*g) ^ ((c16&7)<<3)]);
      #pragma unroll
      for (int dt = 0; dt < 2; ++dt){
        short8 vf = *reinterpret_cast<const short8*>(&Vl[(dt*16 + c16)*264 + tc*32 + 8*g]);
        oacc[dt] = MFMA(pf, vf, oacc[dt], 0, 0, 0);
      }
    }
  }

  // ---- epilogue: LEPE from LDS halo; write att hi/lo region-major ----
  const int tok0 = w*16 + 4*g;
  const int ty = tok0>>3, tx0 = tok0&7;
  #pragma unroll
  for (int dt = 0; dt < 2; ++dt){
    const int cl = dt*16 + c16;
    float wl[9];
    #pragma unroll
    for (int kk = 0; kk < 9; ++kk) wl[kk] = wl_s[cl*9 + kk];
    const float bl = bl_s[cl];
    float vwin[3][6];
    #pragma unroll
    for (int dy = 0; dy < 3; ++dy)
      #pragma unroll
      for (int jj = 0; jj < 6; ++jj)
        vwin[dy][jj] = bf2f(halo[cl*130 + (ty+dy)*13 + tx0 + jj]);
    #pragma unroll
    for (int r = 0; r < 4; ++r){
      float a = oacc[dt][r] + bl;
      #pragma unroll
      for (int dy = 0; dy < 3; ++dy)
        #pragma unroll
        for (int dx = 0; dx < 3; ++dx)
          a += wl[dy*3 + dx] * vwin[dy][r + dx];
      int tok = tok0 + r;
      size_t o = ((size_t)(n*49 + qreg)*64 + tok)*256 + h*32 + dt*16 + c16;
      unsigned short hi = f2bf(a);
      att_hi[o] = hi;
      att_lo[o] = f2bf(a - bf2f(hi));
    }
  }
}

// ---------------- output projection (bf16x3 split; region-major input) ----------------
__global__ __launch_bounds__(256) void k_oproj(const unsigned short* __restrict__ ah_,
                                               const unsigned short* __restrict__ al_,
                                               const unsigned short* __restrict__ wh_,
                                               const unsigned short* __restrict__ wl_,
                                               const float* __restrict__ b_out,
                                               float* __restrict__ out){
  // grid (49 regions, 16 n)
  const int reg = blockIdx.x, n = blockIdx.y;
  const int t = threadIdx.x, w = t>>6, g = (t>>4)&3, c16 = t&15;
  const int ry = reg/7, rx = reg%7;
  const size_t ibase = ((size_t)(n*49 + reg)*64 + c16)*256;
  for (int ot = 0; ot < 4; ++ot){
    const int os = ot*64 + w*16;
    const unsigned short* whb = wh_ + (size_t)(os + c16)*256;
    const unsigned short* wlb = wl_ + (size_t)(os + c16)*256;
    f32x4 acc[4] = {};
    #pragma unroll
    for (int kc = 0; kc < 8; ++kc){
      short8 wh = *reinterpret_cast<const short8*>(whb + kc*32 + 8*g);
      short8 wl = *reinterpret_cast<const short8*>(wlb + kc*32 + 8*g);
      #pragma unroll
      for (int pt = 0; pt < 4; ++pt){
        size_t off = ibase + (size_t)pt*16*256 + kc*32 + 8*g;
        short8 xh = *reinterpret_cast<const short8*>(ah_ + off);
        short8 xl = *reinterpret_cast<const short8*>(al_ + off);
        acc[pt] = MFMA(wh, xh, acc[pt], 0, 0, 0);
        acc[pt] = MFMA(wh, xl, acc[pt], 0, 0, 0);
        acc[pt] = MFMA(wl, xh, acc[pt], 0, 0, 0);
      }
    }
    #pragma unroll
    for (int r = 0; r < 4; ++r){
      int o = os + 4*g + r;
      float bias = b_out[o];
      #pragma unroll
      for (int pt = 0; pt < 4; ++pt){
        int tok = pt*16 + c16;
        int p = (ry*8 + (tok>>3))*56 + rx*8 + (tok&7);
        out[((size_t)n*256 + o)*3136 + p] = acc[pt][r] + bias;
      }
    }
  }
}

extern "C" void kernel_launch(void* const* d_in, const int* in_sizes, int n_in,
                              void* d_out, int out_size, void* d_ws, size_t ws_size,
                              hipStream_t stream){
  const float* x      = (const float*)d_in[0];
  const float* w_qkv  = (const float*)d_in[1];
  const float* b_qkv  = (const float*)d_in[2];
  const float* w_lepe = (const float*)d_in[3];
  const float* b_lepe = (const float*)d_in[4];
  const float* w_out  = (const float*)d_in[5];
  const float* b_out  = (const float*)d_in[6];
  float* out = (float*)d_out;

  char* ws = (char*)d_ws;
  size_t off = 0;
  auto take = [&](size_t bytes)->char*{
    char* p = ws + off; off += (bytes + 255) & ~(size_t)255; return p;
  };
  const size_t TEN = (size_t)16*3136*256*2; // bf16 full tensor
  unsigned short* q_rm   = (unsigned short*)take(TEN);
  unsigned short* k_rm   = (unsigned short*)take(TEN);
  unsigned short* v_rm   = (unsigned short*)take(TEN);
  unsigned short* v_cm   = (unsigned short*)take(TEN);
  unsigned short* att_hi = (unsigned short*)take(TEN);
  unsigned short* att_lo = (unsigned short*)take(TEN);
  float* xbar = (float*)take((size_t)16*49*256*4);
  float* q_r  = (float*)take((size_t)16*49*256*4);
  float* k_r  = (float*)take((size_t)16*49*256*4);
  int*   idxb = (int*)take((size_t)16*49*4*4);
  unsigned short* wqh = (unsigned short*)take((size_t)768*256*2);
  unsigned short* woh = (unsigned short*)take((size_t)256*256*2);
  unsigned short* wol = (unsigned short*)take((size_t)256*256*2);

  k_prep <<<dim3(1024), 256, 0, stream>>>(w_qkv, w_out, wqh, woh, wol);
  k_xbar <<<dim3(7, 16), 256, 0, stream>>>(x, xbar);
  k_qrkr <<<dim3(8, 16), 256, 0, stream>>>(xbar, w_qkv, b_qkv, q_r, k_r);
  k_topk <<<dim3(49, 16), 64, 0, stream>>>(q_r, k_r, idxb);
  k_qkv  <<<dim3(49, 16), 256, 0, stream>>>(x, wqh, b_qkv, q_rm, k_rm, v_rm, v_cm);
  k_attn <<<dim3(49, 8, 16), 256, 0, stream>>>(q_rm, k_rm, v_rm, v_cm, idxb, w_lepe, b_lepe, att_hi, att_lo);
  k_oproj<<<dim3(49, 16), 256, 0, stream>>>(att_hi, att_lo, woh, wol, b_out, out);
}

// Round 5
// 393.624 us; speedup vs baseline: 1.2243x; 1.2243x over previous
//
#include <hip/hip_runtime.h>
#include <cstdint>

#define DEV __device__ __forceinline__

using short8 = __attribute__((ext_vector_type(8))) short;
using f32x4  = __attribute__((ext_vector_type(4))) float;

#define MFMA __builtin_amdgcn_mfma_f32_16x16x32_bf16

DEV float bf2f(unsigned short u){
  union { unsigned int i; float f; } v; v.i = ((unsigned int)u) << 16; return v.f;
}
DEV unsigned short f2bf(float f){
  union { float f; unsigned int i; } v; v.f = f;
  unsigned int x = v.i;
  return (unsigned short)((x + 0x7fffu + ((x >> 16) & 1u)) >> 16);
}

// ---------------- prep: bf16 (hi/lo) splits of weights ----------------
__global__ __launch_bounds__(256) void k_prep(const float* __restrict__ w_qkv,
                                              const float* __restrict__ w_out,
                                              unsigned short* __restrict__ wqh,
                                              unsigned short* __restrict__ woh,
                                              unsigned short* __restrict__ wol){
  int i = blockIdx.x*256 + threadIdx.x;
  if (i < 196608){
    wqh[i] = f2bf(w_qkv[i]);
  } else {
    int j = i - 196608;
    if (j < 65536){
      float v = w_out[j];
      unsigned short h = f2bf(v);
      woh[j] = h;
      wol[j] = f2bf(v - bf2f(h));
    }
  }
}

// ---------------- region means of x (fp32 exact, coalesced rows) ----------------
__global__ __launch_bounds__(256) void k_xbar(const float* __restrict__ x,
                                              float* __restrict__ xbar){
  // grid (7 ry, 16 n); 256 thr = 4 c-groups x 64 lanes
  const int ry = blockIdx.x, n = blockIdx.y;
  const int t = threadIdx.x, cg = t>>6, lane = t&63;
  for (int ci = 0; ci < 64; ++ci){
    int c = ci*4 + cg;
    const float* base = x + ((size_t)n*256 + c)*3136 + ry*8*56;
    float acc = 0.f;
    if (lane < 56){
      #pragma unroll
      for (int yy = 0; yy < 8; ++yy) acc += base[yy*56 + lane];
    }
    acc += __shfl_xor(acc, 1, 64);
    acc += __shfl_xor(acc, 2, 64);
    acc += __shfl_xor(acc, 4, 64);
    if ((lane&7) == 0 && lane < 56)
      xbar[((size_t)n*49 + ry*7 + (lane>>3))*256 + c] = acc * (1.0f/64.0f);
  }
}

// ---------------- q_r / k_r = W_{q,k} * xbar + b (fp32; W read once) ----------------
__global__ __launch_bounds__(256) void k_qrkr(const float* __restrict__ xbar,
                                              const float* __restrict__ w_qkv,
                                              const float* __restrict__ b_qkv,
                                              float* __restrict__ q_r,
                                              float* __restrict__ k_r){
  // grid (8 wchunks, 16 n); 256 thr = 64 rows x 4 k-lanes
  __shared__ float4 xb4[3136]; // 49 regions x 64 float4
  const int wb = blockIdx.x, n = blockIdx.y, t = threadIdx.x;
  {
    const float4* src = (const float4*)(xbar + (size_t)n*12544);
    for (int i = t; i < 3136; i += 256) xb4[i] = src[i];
  }
  const int wrow = wb*64 + (t>>2), kl = t&3;
  float4 wreg[16];
  {
    const float4* wsrc = (const float4*)(w_qkv + (size_t)wrow*256) + kl*16;
    #pragma unroll
    for (int i = 0; i < 16; ++i) wreg[i] = wsrc[i];
  }
  __syncthreads();
  const float bias = b_qkv[wrow];
  for (int reg = 0; reg < 49; ++reg){
    float s = 0.f;
    #pragma unroll
    for (int i = 0; i < 16; ++i){
      float4 a = wreg[i], b = xb4[reg*64 + kl*16 + i];
      s += a.x*b.x + a.y*b.y + a.z*b.z + a.w*b.w;
    }
    s += __shfl_xor(s, 1, 64);
    s += __shfl_xor(s, 2, 64);
    if (kl == 0){
      if (wrow < 256) q_r[((size_t)n*49 + reg)*256 + wrow] = s + bias;
      else            k_r[((size_t)n*49 + reg)*256 + wrow - 256] = s + bias;
    }
  }
}

// ---------------- routing scores + top-4 (ties: lowest index first) ----------------
__global__ __launch_bounds__(64) void k_topk(const float* __restrict__ q_r,
                                             const float* __restrict__ k_r,
                                             int* __restrict__ idx){
  __shared__ float sc[49];
  const int qreg = blockIdx.x, n = blockIdx.y, l = threadIdx.x;
  const float* qrow = q_r + ((size_t)n*49 + qreg)*256;
  const float q0 = qrow[l], q1 = qrow[l+64], q2 = qrow[l+128], q3 = qrow[l+192];
  for (int kr = 0; kr < 49; ++kr){
    const float* krow = k_r + ((size_t)n*49 + kr)*256;
    float s = q0*krow[l] + q1*krow[l+64] + q2*krow[l+128] + q3*krow[l+192];
    #pragma unroll
    for (int m = 1; m < 64; m <<= 1) s += __shfl_xor(s, m, 64);
    if (l == 0) sc[kr] = s;
  }
  __syncthreads();
  if (l == 0){
    #pragma unroll
    for (int s = 0; s < 4; ++s){
      float best = -3.4e38f; int bi = 0;
      for (int kr = 0; kr < 49; ++kr) if (sc[kr] > best){ best = sc[kr]; bi = kr; }
      idx[((size_t)n*49 + qreg)*4 + s] = bi;
      sc[bi] = -3.4e38f;
    }
  }
}

// ---------------- qkv 1x1 conv GEMM, region-aligned tiles ----------------
// q_rm/k_rm: [n][h][reg][64 tok][32 d]; v_rm: [n][h][reg][32 ch][64 tok]
__global__ __launch_bounds__(256) void k_qkv(const float* __restrict__ x,
                                             const unsigned short* __restrict__ wqh,
                                             const float* __restrict__ b_qkv,
                                             unsigned short* __restrict__ q_rm,
                                             unsigned short* __restrict__ k_rm,
                                             unsigned short* __restrict__ v_rm){
  // grid (49 regions, 16 n)
  __shared__ unsigned short xl[64*256]; // [tok][c], ushort idx ^= (tok&15)<<3
  const int reg = blockIdx.x, n = blockIdx.y;
  const int ry = reg/7, rx = reg%7;
  const int t = threadIdx.x, w = t>>6, g = (t>>4)&3, c16 = t&15;
  {
    const int pq = (t & 15)*4, cc = t >> 4;   // token quad, channel
    const int row = pq >> 3, col = pq & 7;
    const float* src = x + ((size_t)n*256 + cc)*3136 + (ry*8 + row)*56 + rx*8 + col;
    for (int ci = 0; ci < 16; ++ci){
      float4 v4 = *reinterpret_cast<const float4*>(src + (size_t)ci*16*3136);
      int c = ci*16 + cc;
      xl[((pq+0)*256 + c) ^ (((pq+0)&15)<<3)] = f2bf(v4.x);
      xl[((pq+1)*256 + c) ^ (((pq+1)&15)<<3)] = f2bf(v4.y);
      xl[((pq+2)*256 + c) ^ (((pq+2)&15)<<3)] = f2bf(v4.z);
      xl[((pq+3)*256 + c) ^ (((pq+3)&15)<<3)] = f2bf(v4.w);
    }
  }
  __syncthreads();
  const size_t rb = (size_t)(n*8)*49 + reg;  // + h*49 per head

  // ---- q/k: 8 o-tiles; D rows = tok (4g+r), cols = o (c16) ----
  for (int ot = 0; ot < 8; ++ot){
    const int os = ot*64 + w*16;
    f32x4 acc[4] = {};
    const unsigned short* wbase = wqh + (size_t)(os + c16)*256;
    #pragma unroll
    for (int kc = 0; kc < 8; ++kc){
      short8 wf = *reinterpret_cast<const short8*>(wbase + kc*32 + 8*g);
      #pragma unroll
      for (int pt = 0; pt < 4; ++pt){
        int p = pt*16 + c16;
        short8 xf = *reinterpret_cast<const short8*>(&xl[(p*256 + kc*32 + 8*g) ^ ((p&15)<<3)]);
        acc[pt] = MFMA(xf, wf, acc[pt], 0, 0, 0);
      }
    }
    const int o = os + c16;
    const float bias = b_qkv[o];
    const int oc = o & 255, hh = oc >> 5, dd = oc & 31;
    unsigned short* dst = ((o < 256) ? q_rm : k_rm) + (rb + hh*49)*2048 + dd;
    #pragma unroll
    for (int pt = 0; pt < 4; ++pt)
      #pragma unroll
      for (int r = 0; r < 4; ++r){
        int tok = pt*16 + 4*g + r;
        dst[tok*32] = f2bf(acc[pt][r] + bias);
      }
  }

  // ---- v: 4 o-tiles; D rows = ch (4g+r), cols = tok (c16) ----
  for (int ot = 0; ot < 4; ++ot){
    const int os = ot*64 + w*16;
    f32x4 acc[4] = {};
    const unsigned short* wbase = wqh + (size_t)(512 + os + c16)*256;
    #pragma unroll
    for (int kc = 0; kc < 8; ++kc){
      short8 wf = *reinterpret_cast<const short8*>(wbase + kc*32 + 8*g);
      #pragma unroll
      for (int pt = 0; pt < 4; ++pt){
        int p = pt*16 + c16;
        short8 xf = *reinterpret_cast<const short8*>(&xl[(p*256 + kc*32 + 8*g) ^ ((p&15)<<3)]);
        acc[pt] = MFMA(wf, xf, acc[pt], 0, 0, 0);
      }
    }
    #pragma unroll
    for (int r = 0; r < 4; ++r){
      int c = os + 4*g + r;
      const float bias = b_qkv[512 + c];
      int hh = c >> 5, ch = c & 31;
      unsigned short* dst = v_rm + (rb + hh*49)*2048 + ch*64;
      #pragma unroll
      for (int pt = 0; pt < 4; ++pt)
        dst[pt*16 + c16] = f2bf(acc[pt][r] + bias);
    }
  }
}

// ---------------- attention + fused LEPE per (n, head, region) ----------------
__global__ __launch_bounds__(256) void k_attn(const unsigned short* __restrict__ q_rm,
                                              const unsigned short* __restrict__ k_rm,
                                              const unsigned short* __restrict__ v_rm,
                                              const int* __restrict__ idx,
                                              const float* __restrict__ w_lepe,
                                              const float* __restrict__ b_lepe,
                                              unsigned short* __restrict__ att_hi,
                                              unsigned short* __restrict__ att_lo){
  __shared__ unsigned short Kl[256*40];   // [gathered tok][32d], 80B row stride
  __shared__ unsigned short Vl[32*264];   // [ch][gathered tok], 264 stride
  __shared__ unsigned short Pw[4*2048];   // per-wave [16 q][128 k], swizzled
  __shared__ unsigned short halo[4160];   // [32 c][10 y][13 x]
  __shared__ float wl_s[288];
  __shared__ float bl_s[32];

  // XCD-aware remap: all 49 qreg-blocks of one (h,n) on one XCD, consecutive.
  const int lin = blockIdx.x + 49*(blockIdx.y + 8*blockIdx.z);
  const int xcd = lin & 7, j = lin >> 3;
  const int jq = j / 49;
  const int qreg = j - jq*49;
  const int hn = jq*8 + xcd;
  const int h = hn & 7, n = hn >> 3;

  const int t = threadIdx.x, w = t>>6, g = (t>>4)&3, c16 = t&15;
  const int ry = qreg/7, rx = qreg%7;
  const int gy0 = ry*8, gx0 = rx*8;

  int regs[4];
  #pragma unroll
  for (int s = 0; s < 4; ++s) regs[s] = idx[((size_t)n*49 + qreg)*4 + s];

  const size_t hb = ((size_t)(n*8 + h))*49;

  // ---- stage K: 4 regions x 64 tok x 64B, coalesced ----
  {
    const int rr = t>>6, tloc = t&63;
    const unsigned short* src = k_rm + (hb + regs[rr])*2048 + tloc*32;
    unsigned short* dst = &Kl[(rr*64 + tloc)*40];
    #pragma unroll
    for (int jj = 0; jj < 4; ++jj)
      *reinterpret_cast<short8*>(dst + jj*8) = *reinterpret_cast<const short8*>(src + jj*8);
  }
  // ---- stage V: 4 regions x 32ch x 64tok, coalesced ----
  {
    const int ch = t>>3, tl8 = (t&7)*8;
    #pragma unroll
    for (int rr = 0; rr < 4; ++rr){
      const unsigned short* src = v_rm + (hb + regs[rr])*2048 + ch*64 + tl8;
      *reinterpret_cast<short8*>(&Vl[ch*264 + rr*64 + tl8]) =
          *reinterpret_cast<const short8*>(src);
    }
  }
  // ---- stage LEPE weights + v halo (from region-major v_rm) ----
  wl_s[t < 288 ? t : 0] = w_lepe[h*288 + (t < 288 ? t : 0)];
  if (t < 32){
    wl_s[256 + t] = w_lepe[h*288 + 256 + t];
    bl_s[t] = b_lepe[h*32 + t];
  }
  for (int seg = t; seg < 320; seg += 256){
    int c = seg/10, row = seg - (seg/10)*10;
    int yy = gy0 + row - 1;
    unsigned short* drow = &halo[c*130 + row*13];
    #pragma unroll
    for (int jj = 0; jj < 10; ++jj){
      int xx = gx0 - 1 + jj;
      unsigned short v = 0;
      if (yy >= 0 && yy < 56 && xx >= 0 && xx < 56){
        int iry = yy>>3, irx = xx>>3, tk = ((yy&7)<<3) + (xx&7);
        v = v_rm[(hb + iry*7 + irx)*2048 + c*64 + tk];
      }
      drow[jj] = v;
    }
  }
  __syncthreads();

  // ---- Q frag (contiguous region-major global read) ----
  const int qtok = w*16 + c16;
  short8 qf = *reinterpret_cast<const short8*>(q_rm + (hb + qreg)*2048 + qtok*32 + 8*g);

  // ---- QK^T from LDS ----
  f32x4 s_acc[16];
  #pragma unroll
  for (int f = 0; f < 16; ++f){
    short8 kf = *reinterpret_cast<const short8*>(&Kl[(f*16 + c16)*40 + 8*g]);
    f32x4 z = {0.f, 0.f, 0.f, 0.f};
    s_acc[f] = MFMA(qf, kf, z, 0, 0, 0);
  }
  const float scale = 0.1767766952966369f; // 32^-0.5
  #pragma unroll
  for (int f = 0; f < 16; ++f) s_acc[f] = s_acc[f] * scale;

  // ---- softmax over 256 keys per row (row = w*16 + 4g + r) ----
  float inv[4];
  #pragma unroll
  for (int r = 0; r < 4; ++r){
    float m = -3.4e38f;
    #pragma unroll
    for (int f = 0; f < 16; ++f) m = fmaxf(m, s_acc[f][r]);
    #pragma unroll
    for (int d = 1; d < 16; d <<= 1) m = fmaxf(m, __shfl_xor(m, d, 64));
    float su = 0.f;
    #pragma unroll
    for (int f = 0; f < 16; ++f){ float e = __expf(s_acc[f][r] - m); s_acc[f][r] = e; su += e; }
    #pragma unroll
    for (int d = 1; d < 16; d <<= 1) su += __shfl_xor(su, d, 64);
    inv[r] = 1.0f / su;
  }

  // ---- PV in two k-halves: per-wave P staging (no block barrier) ----
  f32x4 oacc[2] = {};
  unsigned short* wb2 = &Pw[w*2048];
  #pragma unroll
  for (int h2 = 0; h2 < 2; ++h2){
    #pragma unroll
    for (int f2 = 0; f2 < 8; ++f2){
      int f = 8*h2 + f2;
      #pragma unroll
      for (int r = 0; r < 4; ++r){
        int q = 4*g + r;
        wb2[(q*128 + f2*16 + c16) ^ ((q&7)<<3)] = f2bf(s_acc[f][r] * inv[r]);
      }
    }
    asm volatile("s_waitcnt lgkmcnt(0)" ::: "memory");
    __builtin_amdgcn_sched_barrier(0);
    #pragma unroll
    for (int tcl = 0; tcl < 4; ++tcl){
      const int tc = 4*h2 + tcl;
      short8 pf = *reinterpret_cast<const short8*>(&wb2[(c16*128 + tcl*32 + 8*g) ^ ((c16&7)<<3)]);
      #pragma unroll
      for (int dt = 0; dt < 2; ++dt){
        short8 vf = *reinterpret_cast<const short8*>(&Vl[(dt*16 + c16)*264 + tc*32 + 8*g]);
        oacc[dt] = MFMA(pf, vf, oacc[dt], 0, 0, 0);
      }
    }
  }

  // ---- epilogue: LEPE from LDS halo; write att hi/lo region-major ----
  const int tok0 = w*16 + 4*g;
  const int ty = tok0>>3, tx0 = tok0&7;
  #pragma unroll
  for (int dt = 0; dt < 2; ++dt){
    const int cl = dt*16 + c16;
    float wl[9];
    #pragma unroll
    for (int kk = 0; kk < 9; ++kk) wl[kk] = wl_s[cl*9 + kk];
    const float bl = bl_s[cl];
    float vwin[3][6];
    #pragma unroll
    for (int dy = 0; dy < 3; ++dy)
      #pragma unroll
      for (int jj = 0; jj < 6; ++jj)
        vwin[dy][jj] = bf2f(halo[cl*130 + (ty+dy)*13 + tx0 + jj]);
    #pragma unroll
    for (int r = 0; r < 4; ++r){
      float a = oacc[dt][r] + bl;
      #pragma unroll
      for (int dy = 0; dy < 3; ++dy)
        #pragma unroll
        for (int dx = 0; dx < 3; ++dx)
          a += wl[dy*3 + dx] * vwin[dy][r + dx];
      int tok = tok0 + r;
      size_t o = ((size_t)(n*49 + qreg)*64 + tok)*256 + h*32 + dt*16 + c16;
      unsigned short hi = f2bf(a);
      att_hi[o] = hi;
      att_lo[o] = f2bf(a - bf2f(hi));
    }
  }
}

// ---------------- output projection (bf16x3 split; region-major input) ----------------
__global__ __launch_bounds__(256) void k_oproj(const unsigned short* __restrict__ ah_,
                                               const unsigned short* __restrict__ al_,
                                               const unsigned short* __restrict__ wh_,
                                               const unsigned short* __restrict__ wl_,
                                               const float* __restrict__ b_out,
                                               float* __restrict__ out){
  // grid (49 regions, 16 n)
  const int reg = blockIdx.x, n = blockIdx.y;
  const int t = threadIdx.x, w = t>>6, g = (t>>4)&3, c16 = t&15;
  const int ry = reg/7, rx = reg%7;
  const size_t ibase = ((size_t)(n*49 + reg)*64 + c16)*256;
  for (int ot = 0; ot < 4; ++ot){
    const int os = ot*64 + w*16;
    const unsigned short* whb = wh_ + (size_t)(os + c16)*256;
    const unsigned short* wlb = wl_ + (size_t)(os + c16)*256;
    f32x4 acc[4] = {};
    #pragma unroll
    for (int kc = 0; kc < 8; ++kc){
      short8 wh = *reinterpret_cast<const short8*>(whb + kc*32 + 8*g);
      short8 wl = *reinterpret_cast<const short8*>(wlb + kc*32 + 8*g);
      #pragma unroll
      for (int pt = 0; pt < 4; ++pt){
        size_t off = ibase + (size_t)pt*16*256 + kc*32 + 8*g;
        short8 xh = *reinterpret_cast<const short8*>(ah_ + off);
        short8 xl = *reinterpret_cast<const short8*>(al_ + off);
        acc[pt] = MFMA(wh, xh, acc[pt], 0, 0, 0);
        acc[pt] = MFMA(wh, xl, acc[pt], 0, 0, 0);
        acc[pt] = MFMA(wl, xh, acc[pt], 0, 0, 0);
      }
    }
    #pragma unroll
    for (int r = 0; r < 4; ++r){
      int o = os + 4*g + r;
      float bias = b_out[o];
      #pragma unroll
      for (int pt = 0; pt < 4; ++pt){
        int tok = pt*16 + c16;
        int p = (ry*8 + (tok>>3))*56 + rx*8 + (tok&7);
        out[((size_t)n*256 + o)*3136 + p] = acc[pt][r] + bias;
      }
    }
  }
}

extern "C" void kernel_launch(void* const* d_in, const int* in_sizes, int n_in,
                              void* d_out, int out_size, void* d_ws, size_t ws_size,
                              hipStream_t stream){
  const float* x      = (const float*)d_in[0];
  const float* w_qkv  = (const float*)d_in[1];
  const float* b_qkv  = (const float*)d_in[2];
  const float* w_lepe = (const float*)d_in[3];
  const float* b_lepe = (const float*)d_in[4];
  const float* w_out  = (const float*)d_in[5];
  const float* b_out  = (const float*)d_in[6];
  float* out = (float*)d_out;

  char* ws = (char*)d_ws;
  size_t off = 0;
  auto take = [&](size_t bytes)->char*{
    char* p = ws + off; off += (bytes + 255) & ~(size_t)255; return p;
  };
  const size_t TEN = (size_t)16*3136*256*2; // bf16 full tensor
  unsigned short* q_rm   = (unsigned short*)take(TEN);
  unsigned short* k_rm   = (unsigned short*)take(TEN);
  unsigned short* v_rm   = (unsigned short*)take(TEN);
  unsigned short* att_hi = (unsigned short*)take(TEN);
  unsigned short* att_lo = (unsigned short*)take(TEN);
  float* xbar = (float*)take((size_t)16*49*256*4);
  float* q_r  = (float*)take((size_t)16*49*256*4);
  float* k_r  = (float*)take((size_t)16*49*256*4);
  int*   idxb = (int*)take((size_t)16*49*4*4);
  unsigned short* wqh = (unsigned short*)take((size_t)768*256*2);
  unsigned short* woh = (unsigned short*)take((size_t)256*256*2);
  unsigned short* wol = (unsigned short*)take((size_t)256*256*2);

  k_prep <<<dim3(1024), 256, 0, stream>>>(w_qkv, w_out, wqh, woh, wol);
  k_xbar <<<dim3(7, 16), 256, 0, stream>>>(x, xbar);
  k_qrkr <<<dim3(8, 16), 256, 0, stream>>>(xbar, w_qkv, b_qkv, q_r, k_r);
  k_topk <<<dim3(49, 16), 64, 0, stream>>>(q_r, k_r, idxb);
  k_qkv  <<<dim3(49, 16), 256, 0, stream>>>(x, wqh, b_qkv, q_rm, k_rm, v_rm);
  k_attn <<<dim3(49, 8, 16), 256, 0, stream>>>(q_rm, k_rm, v_rm, idxb, w_lepe, b_lepe, att_hi, att_lo);
  k_oproj<<<dim3(49, 16), 256, 0, stream>>>(att_hi, att_lo, woh, wol, b_out, out);
}